// Round 1
// baseline (416.160 us; speedup 1.0000x reference)
//
#include <hip/hip_runtime.h>

#define BB   64
#define TT   256
#define EMBD 300
#define HIDD 512
#define OUTC 10
#define CT   16
#define THETA 10.0
#define FUTN 12   // >= actual refractory length-1 (expected 10)

// ---------------- Layer 1: gather + W1 GEMM + psp FIR + spike scan ----------
struct S1A { float x[TT][33]; float w[CT][32]; };          // staging for GEMM
struct S1B { double h[CT][257]; float s[CT][257]; };       // membrane + spikes
union  SmemL1 { S1A a; S1B b; };

__global__ __launch_bounds__(256)
void layer1_kernel(const int* __restrict__ feed, const float* __restrict__ emb,
                   const float* __restrict__ W1, const float* __restrict__ srm,
                   const float* __restrict__ refk, float* __restrict__ s1,
                   int Ks, int Kr)
{
    __shared__ SmemL1 sm;
    __shared__ int    idxb[TT];
    __shared__ double srm_sm[TT];

    const int tid = threadIdx.x;      // == t index for compute phases
    const int b   = blockIdx.x;
    const int c0  = blockIdx.y * CT;

    idxb[tid]   = feed[b * TT + tid];
    srm_sm[tid] = (tid < Ks) ? (double)srm[tid] : 0.0;
    __syncthreads();

    double acc[CT];
#pragma unroll
    for (int c = 0; c < CT; ++c) acc[c] = 0.0;

    const int e_lane = tid & 31;
    const int t_row  = tid >> 5;

    for (int e0 = 0; e0 < EMBD; e0 += 32) {
        const int ec = min(32, EMBD - e0);
        // stage x chunk: x[t][e] = emb[feed[b,t], e0+e]  (coalesced over e)
        if (e_lane < ec) {
#pragma unroll
            for (int p = 0; p < 32; ++p) {
                const int t = t_row + (p << 3);
                sm.a.x[t][e_lane] = emb[(size_t)idxb[t] * EMBD + e0 + e_lane];
            }
        }
        // stage W1 chunk
        for (int j = tid; j < CT * 32; j += 256) {
            const int c = j >> 5, ee = j & 31;
            if (ee < ec) sm.a.w[c][ee] = W1[(size_t)(c0 + c) * EMBD + e0 + ee];
        }
        __syncthreads();
        for (int e = 0; e < ec; ++e) {
            const double xv = (double)sm.a.x[tid][e];
#pragma unroll
            for (int c = 0; c < CT; ++c)
                acc[c] = fma(xv, (double)sm.a.w[c][e], acc[c]);
        }
        __syncthreads();
    }

    // membrane (pre-psp) -> LDS
#pragma unroll
    for (int c = 0; c < CT; ++c) sm.b.h[c][tid] = acc[c];
    __syncthreads();

    // psp FIR: u[t] = sum_j h[t-j]*srm[j]
    double p2[CT];
#pragma unroll
    for (int c = 0; c < CT; ++c) p2[c] = 0.0;
    const int jmax = min(tid, Ks - 1);
    for (int j = 0; j <= jmax; ++j) {
        const double sj = srm_sm[j];
#pragma unroll
        for (int c = 0; c < CT; ++c)
            p2[c] = fma(sm.b.h[c][tid - j], sj, p2[c]);
    }
    __syncthreads();
#pragma unroll
    for (int c = 0; c < CT; ++c) sm.b.h[c][tid] = p2[c];
    __syncthreads();

    // sequential spike scan (16 lanes, one per channel)
    if (tid < CT) {
        double fut[FUTN];
#pragma unroll
        for (int i = 0; i < FUTN; ++i)
            fut[i] = (i + 1 < Kr) ? (double)refk[i + 1] : 0.0;
        double r[FUTN];
#pragma unroll
        for (int i = 0; i < FUTN; ++i) r[i] = 0.0;
        for (int t = 0; t < TT; ++t) {
            const double m  = sm.b.h[tid][t] + r[0];
            const double sv = (m >= THETA) ? 1.0 : 0.0;
#pragma unroll
            for (int i = 0; i < FUTN - 1; ++i) r[i] = fma(sv, fut[i], r[i + 1]);
            r[FUTN - 1] = sv * fut[FUTN - 1];
            sm.b.s[tid][t] = (float)sv;
        }
    }
    __syncthreads();
#pragma unroll
    for (int c = 0; c < CT; ++c)
        s1[((size_t)b * HIDD + c0 + c) * TT + tid] = sm.b.s[c][tid];
}

// ---------------- Layer 2: W2 GEMM on spikes + psp FIR + spike scan ---------
struct S2B { double h[OUTC][257]; float s[OUTC][257]; };
union  SmemL2 { float w[OUTC][HIDD]; S2B b; };

__global__ __launch_bounds__(256)
void layer2_kernel(const float* __restrict__ s1, const float* __restrict__ W2,
                   const float* __restrict__ srm, const float* __restrict__ refk,
                   float* __restrict__ out, int Ks, int Kr)
{
    __shared__ SmemL2 sm;
    __shared__ double srm_sm[TT];

    const int tid = threadIdx.x;   // == t index
    const int b   = blockIdx.x;

    srm_sm[tid] = (tid < Ks) ? (double)srm[tid] : 0.0;
    for (int j = tid; j < OUTC * HIDD; j += 256) ((float*)sm.w)[j] = W2[j];
    __syncthreads();

    double acc[OUTC];
#pragma unroll
    for (int oc = 0; oc < OUTC; ++oc) acc[oc] = 0.0;

    const float* srow = s1 + (size_t)b * HIDD * TT + tid;
#pragma unroll 4
    for (int h = 0; h < HIDD; ++h) {
        const double sv = (double)srow[(size_t)h * TT];
#pragma unroll
        for (int oc = 0; oc < OUTC; ++oc)
            acc[oc] = fma(sv, (double)sm.w[oc][h], acc[oc]);
    }
    __syncthreads();   // done reading W2; reuse LDS

#pragma unroll
    for (int oc = 0; oc < OUTC; ++oc) sm.b.h[oc][tid] = acc[oc];
    __syncthreads();

    double p2[OUTC];
#pragma unroll
    for (int oc = 0; oc < OUTC; ++oc) p2[oc] = 0.0;
    const int jmax = min(tid, Ks - 1);
    for (int j = 0; j <= jmax; ++j) {
        const double sj = srm_sm[j];
#pragma unroll
        for (int oc = 0; oc < OUTC; ++oc)
            p2[oc] = fma(sm.b.h[oc][tid - j], sj, p2[oc]);
    }
    __syncthreads();
#pragma unroll
    for (int oc = 0; oc < OUTC; ++oc) sm.b.h[oc][tid] = p2[oc];
    __syncthreads();

    if (tid < OUTC) {
        double fut[FUTN];
#pragma unroll
        for (int i = 0; i < FUTN; ++i)
            fut[i] = (i + 1 < Kr) ? (double)refk[i + 1] : 0.0;
        double r[FUTN];
#pragma unroll
        for (int i = 0; i < FUTN; ++i) r[i] = 0.0;
        for (int t = 0; t < TT; ++t) {
            const double m  = sm.b.h[tid][t] + r[0];
            const double sv = (m >= THETA) ? 1.0 : 0.0;
#pragma unroll
            for (int i = 0; i < FUTN - 1; ++i) r[i] = fma(sv, fut[i], r[i + 1]);
            r[FUTN - 1] = sv * fut[FUTN - 1];
            sm.b.s[tid][t] = (float)sv;
        }
    }
    __syncthreads();
#pragma unroll
    for (int oc = 0; oc < OUTC; ++oc)
        out[((size_t)b * OUTC + oc) * TT + tid] = sm.b.s[oc][tid];
}

extern "C" void kernel_launch(void* const* d_in, const int* in_sizes, int n_in,
                              void* d_out, int out_size, void* d_ws, size_t ws_size,
                              hipStream_t stream)
{
    const int*   feed = (const int*)  d_in[0];
    const float* emb  = (const float*)d_in[1];
    const float* W1   = (const float*)d_in[2];
    const float* W2   = (const float*)d_in[3];
    const float* srm  = (const float*)d_in[4];
    const float* refk = (const float*)d_in[5];
    const int Ks = in_sizes[4];
    const int Kr = in_sizes[5];

    float* s1  = (float*)d_ws;                 // B*HID*T f32 spikes = 32 MiB
    float* out = (float*)d_out;

    layer1_kernel<<<dim3(BB, HIDD / CT), 256, 0, stream>>>(
        feed, emb, W1, srm, refk, s1, Ks, Kr);
    layer2_kernel<<<dim3(BB), 256, 0, stream>>>(
        s1, W2, srm, refk, out, Ks, Kr);
}

// Round 2
// 382.915 us; speedup vs baseline: 1.0868x; 1.0868x over previous
//
#include <hip/hip_runtime.h>

#define BB    64
#define TT    256
#define EMBD  300
#define HIDD  512
#define OUTC  10
#define THETA 10.0
#define FUTN  12     // >= Kr-1 (Kr expected 11)
#define KSMAX 80     // >= Ks (expected 77), srm zero-padded
#define HSTRIDE 344  // swizzled h row stride (max swz index 343)

__device__ __forceinline__ int hswz(int tt) { return tt ^ ((tt >> 4) & 7); }

// ---------------- prep: gather+transpose x -> xg[b][e][t] f32; W2 -> f64 ----
__global__ __launch_bounds__(256)
void prep_kernel(const int* __restrict__ feed, const float* __restrict__ emb,
                 const float* __restrict__ W2, float* __restrict__ xg,
                 double* __restrict__ w2d)
{
    if (blockIdx.y == 8) {             // W2 f32 -> f64 (needs 5120 elems)
        const int k = blockIdx.x * 256 + threadIdx.x;
        if (k < OUTC * HIDD) w2d[k] = (double)W2[k];
        return;
    }
    __shared__ float xt[32][305];
    __shared__ int   idx32[32];
    const int tid = threadIdx.x;
    const int b   = blockIdx.x;
    const int t0  = blockIdx.y * 32;

    if (tid < 32) idx32[tid] = feed[b * TT + t0 + tid];
    __syncthreads();
    for (int t = tid >> 6; t < 32; t += 4) {
        const size_t row = (size_t)idx32[t] * EMBD;
        for (int e = (tid & 63); e < EMBD; e += 64)
            xt[t][e] = emb[row + e];
    }
    __syncthreads();
    const int tl = tid & 7;
    for (int e = tid >> 3; e < EMBD; e += 32) {
        float4 v;
        v.x = xt[4 * tl + 0][e];
        v.y = xt[4 * tl + 1][e];
        v.z = xt[4 * tl + 2][e];
        v.w = xt[4 * tl + 3][e];
        *(float4*)&xg[((size_t)b * EMBD + e) * TT + t0 + 4 * tl] = v;
    }
}

// ---------------- layer 1: GEMM (f64 acc) + FIR + spike scan ----------------
__global__ __launch_bounds__(256, 3)
void layer1_kernel(const float* __restrict__ xg, const float* __restrict__ W1,
                   const float* __restrict__ srm, const float* __restrict__ refk,
                   unsigned char* __restrict__ s1, int Ks, int Kr)
{
    __shared__ union {
        float  x[16 * 260];            // [e][t] f32, stride 260
        double h[16 * HSTRIDE];        // [c][swz(tt)] f64
    } A;
    __shared__ union {
        double        w[16 * 34];      // [e][c] f64, stride 34
        unsigned char s[16 * 260];     // spikes
    } B;
    __shared__ double srm_sm[KSMAX];

    const int tid = threadIdx.x;
    const int b   = blockIdx.x;        // x-major => same-b blocks share XCD/L2
    const int c0  = blockIdx.y * 16;

    if (tid < KSMAX) srm_sm[tid] = (tid < Ks) ? (double)srm[tid] : 0.0;

    const int cg = tid & 3,  tg = tid >> 2;    // GEMM tile: c=4cg+j, t=4tg+i
    const int tl = tid & 63, wv = tid >> 6;    // x staging
    const int ew = tid & 15, cw = tid >> 4;    // w staging

    double acc[4][4];
#pragma unroll
    for (int i = 0; i < 4; ++i)
#pragma unroll
        for (int j = 0; j < 4; ++j) acc[i][j] = 0.0;

    float xr[4][4];
    float wr = 0.f;

    // stage chunk 0 (ec = 16)
    {
#pragma unroll
        for (int r = 0; r < 4; ++r)
            *(float4*)xr[r] = *(const float4*)&xg[((size_t)b * EMBD + 4 * wv + r) * TT + 4 * tl];
        wr = W1[(size_t)(c0 + cw) * EMBD + ew];
#pragma unroll
        for (int r = 0; r < 4; ++r)
            *(float4*)&A.x[(4 * wv + r) * 260 + 4 * tl] = *(float4*)xr[r];
        B.w[ew * 34 + cw] = (double)wr;
    }
    __syncthreads();

    const int NCH = (EMBD + 15) / 16;  // 19
    for (int ch = 0; ch < NCH; ++ch) {
        const int ecur = min(16, EMBD - ch * 16);
        const int e0n  = (ch + 1) * 16;
        const int ecn  = EMBD - e0n;
        if (ch + 1 < NCH) {            // prefetch next chunk into registers
#pragma unroll
            for (int r = 0; r < 4; ++r) {
                const int e = 4 * wv + r;
                if (e < ecn)
                    *(float4*)xr[r] = *(const float4*)&xg[((size_t)b * EMBD + e0n + e) * TT + 4 * tl];
            }
            if (ew < ecn) wr = W1[(size_t)(c0 + cw) * EMBD + e0n + ew];
        }
        const float*  xp = &A.x[4 * tg];
        const double* wp = &B.w[4 * cg];
#pragma unroll 4
        for (int e = 0; e < ecur; ++e) {
            const float4  xv = *(const float4*)xp;
            const double2 wa = *(const double2*)wp;
            const double2 wb = *(const double2*)(wp + 2);
            const double xd0 = (double)xv.x, xd1 = (double)xv.y;
            const double xd2 = (double)xv.z, xd3 = (double)xv.w;
            acc[0][0] = fma(xd0, wa.x, acc[0][0]);
            acc[0][1] = fma(xd0, wa.y, acc[0][1]);
            acc[0][2] = fma(xd0, wb.x, acc[0][2]);
            acc[0][3] = fma(xd0, wb.y, acc[0][3]);
            acc[1][0] = fma(xd1, wa.x, acc[1][0]);
            acc[1][1] = fma(xd1, wa.y, acc[1][1]);
            acc[1][2] = fma(xd1, wb.x, acc[1][2]);
            acc[1][3] = fma(xd1, wb.y, acc[1][3]);
            acc[2][0] = fma(xd2, wa.x, acc[2][0]);
            acc[2][1] = fma(xd2, wa.y, acc[2][1]);
            acc[2][2] = fma(xd2, wb.x, acc[2][2]);
            acc[2][3] = fma(xd2, wb.y, acc[2][3]);
            acc[3][0] = fma(xd3, wa.x, acc[3][0]);
            acc[3][1] = fma(xd3, wa.y, acc[3][1]);
            acc[3][2] = fma(xd3, wb.x, acc[3][2]);
            acc[3][3] = fma(xd3, wb.y, acc[3][3]);
            xp += 260;
            wp += 34;
        }
        __syncthreads();               // all reads of bufs done
        if (ch + 1 < NCH) {
#pragma unroll
            for (int r = 0; r < 4; ++r) {
                const int e = 4 * wv + r;
                if (e < ecn)
                    *(float4*)&A.x[e * 260 + 4 * tl] = *(float4*)xr[r];
            }
            if (ew < ecn) B.w[ew * 34 + cw] = (double)wr;
            __syncthreads();
        }
    }

    // h (pre-psp membrane) -> LDS, with 80-deep zero pad in front
    const int cf = tid & 15, tb = tid >> 4;
    if (tb < 5) {
#pragma unroll
        for (int k = 0; k < 16; ++k)
            A.h[cf * HSTRIDE + hswz(tb * 16 + k)] = 0.0;
    }
#pragma unroll
    for (int i = 0; i < 4; ++i)
#pragma unroll
        for (int j = 0; j < 4; ++j)
            A.h[(4 * cg + j) * HSTRIDE + hswz(80 + 4 * tg + i)] = acc[i][j];
    __syncthreads();

    // psp FIR: sliding 16-deep cyclic window, thread = (c=cf, t-range tb*16..+15)
    const int t0f = tb * 16;
    double* hrow = &A.h[cf * HSTRIDE];
    double p[16], win[16];
#pragma unroll
    for (int k = 0; k < 16; ++k) {
        p[k]   = 0.0;
        win[k] = hrow[hswz(80 + t0f + k)];
    }
    for (int jb = 0; jb < KSMAX; jb += 16) {
#pragma unroll
        for (int jj = 0; jj < 16; ++jj) {
            const double sj = srm_sm[jb + jj];
#pragma unroll
            for (int i = 0; i < 16; ++i)
                p[i] = fma(win[(16 + i - jj) & 15], sj, p[i]);
            win[(15 - jj) & 15] = hrow[hswz(80 + t0f - (jb + jj) - 1)];
        }
    }
    __syncthreads();                   // all FIR reads done before overwrite
#pragma unroll
    for (int i = 0; i < 16; ++i)
        hrow[hswz(80 + t0f + i)] = p[i];
    __syncthreads();

    // spike scan: 16 lanes, one per channel
    if (tid < 16) {
        double fut[FUTN], rsh[FUTN];
#pragma unroll
        for (int i = 0; i < FUTN; ++i) {
            fut[i] = (i + 1 < Kr) ? (double)refk[i + 1] : 0.0;
            rsh[i] = 0.0;
        }
        const double*  hr = &A.h[tid * HSTRIDE];
        unsigned char* sr = &B.s[tid * 260];
        for (int t = 0; t < TT; ++t) {
            const double m  = hr[hswz(80 + t)] + rsh[0];
            const double sv = (m >= THETA) ? 1.0 : 0.0;
#pragma unroll
            for (int i = 0; i < FUTN - 1; ++i) rsh[i] = fma(sv, fut[i], rsh[i + 1]);
            rsh[FUTN - 1] = sv * fut[FUTN - 1];
            sr[t] = (unsigned char)(sv != 0.0 ? 1 : 0);
        }
    }
    __syncthreads();

    // spikes -> global (uchar, coalesced via uint)
    {
        const int tl2 = tid & 63;
#pragma unroll
        for (int r = 0; r < 4; ++r) {
            const int c = (tid >> 6) + 4 * r;
            const unsigned int v = *(const unsigned int*)&B.s[c * 260 + 4 * tl2];
            *(unsigned int*)&s1[((size_t)b * HIDD + c0 + c) * TT + 4 * tl2] = v;
        }
    }
}

// ---------------- layer 2: W2 GEMM on spikes + FIR + spike scan -------------
__global__ __launch_bounds__(256)
void layer2_kernel(const unsigned char* __restrict__ s1,
                   const double* __restrict__ w2d,
                   const float* __restrict__ srm, const float* __restrict__ refk,
                   float* __restrict__ out, int Ks, int Kr)
{
    __shared__ double        h2[OUTC * HSTRIDE];
    __shared__ unsigned char s2[OUTC * 260];
    __shared__ double        srm_sm[KSMAX];

    const int tid = threadIdx.x;       // == t
    const int b   = blockIdx.x;

    if (tid < KSMAX) srm_sm[tid] = (tid < Ks) ? (double)srm[tid] : 0.0;

    double acc[OUTC];
#pragma unroll
    for (int oc = 0; oc < OUTC; ++oc) acc[oc] = 0.0;

    const unsigned char* sp = s1 + (size_t)b * HIDD * TT + tid;
#pragma unroll 8
    for (int h = 0; h < HIDD; ++h) {
        const double sv = (double)sp[(size_t)h * TT];
#pragma unroll
        for (int oc = 0; oc < OUTC; ++oc)
            acc[oc] = fma(sv, w2d[oc * HIDD + h], acc[oc]);
    }

    const int cf = tid & 15, tb = tid >> 4;
    if (cf < OUTC && tb < 5) {
#pragma unroll
        for (int k = 0; k < 16; ++k)
            h2[cf * HSTRIDE + hswz(tb * 16 + k)] = 0.0;
    }
#pragma unroll
    for (int oc = 0; oc < OUTC; ++oc)
        h2[oc * HSTRIDE + hswz(80 + tid)] = acc[oc];
    __syncthreads();

    // FIR (threads with cf < OUTC active)
    double p[16], win[16];
    double* hrow = &h2[cf * HSTRIDE];
    const int t0f = tb * 16;
    if (cf < OUTC) {
#pragma unroll
        for (int k = 0; k < 16; ++k) {
            p[k]   = 0.0;
            win[k] = hrow[hswz(80 + t0f + k)];
        }
        for (int jb = 0; jb < KSMAX; jb += 16) {
#pragma unroll
            for (int jj = 0; jj < 16; ++jj) {
                const double sj = srm_sm[jb + jj];
#pragma unroll
                for (int i = 0; i < 16; ++i)
                    p[i] = fma(win[(16 + i - jj) & 15], sj, p[i]);
                win[(15 - jj) & 15] = hrow[hswz(80 + t0f - (jb + jj) - 1)];
            }
        }
    }
    __syncthreads();
    if (cf < OUTC) {
#pragma unroll
        for (int i = 0; i < 16; ++i)
            hrow[hswz(80 + t0f + i)] = p[i];
    }
    __syncthreads();

    if (tid < OUTC) {
        double fut[FUTN], rsh[FUTN];
#pragma unroll
        for (int i = 0; i < FUTN; ++i) {
            fut[i] = (i + 1 < Kr) ? (double)refk[i + 1] : 0.0;
            rsh[i] = 0.0;
        }
        const double*  hr = &h2[tid * HSTRIDE];
        unsigned char* sr = &s2[tid * 260];
        for (int t = 0; t < TT; ++t) {
            const double m  = hr[hswz(80 + t)] + rsh[0];
            const double sv = (m >= THETA) ? 1.0 : 0.0;
#pragma unroll
            for (int i = 0; i < FUTN - 1; ++i) rsh[i] = fma(sv, fut[i], rsh[i + 1]);
            rsh[FUTN - 1] = sv * fut[FUTN - 1];
            sr[t] = (unsigned char)(sv != 0.0 ? 1 : 0);
        }
    }
    __syncthreads();

#pragma unroll
    for (int r = 0; r < OUTC; ++r)
        out[((size_t)b * OUTC + r) * TT + tid] = (float)s2[r * 260 + tid];
}

extern "C" void kernel_launch(void* const* d_in, const int* in_sizes, int n_in,
                              void* d_out, int out_size, void* d_ws, size_t ws_size,
                              hipStream_t stream)
{
    const int*   feed = (const int*)  d_in[0];
    const float* emb  = (const float*)d_in[1];
    const float* W1   = (const float*)d_in[2];
    const float* W2   = (const float*)d_in[3];
    const float* srm  = (const float*)d_in[4];
    const float* refk = (const float*)d_in[5];
    const int Ks = in_sizes[4];
    const int Kr = in_sizes[5];

    unsigned char* s1c = (unsigned char*)d_ws;                       // 8,388,608 B
    float*  xg  = (float*) ((char*)d_ws + 8388608);                  // 19,660,800 B
    double* w2d = (double*)((char*)d_ws + 8388608 + 19660800);       // 40,960 B
    float*  out = (float*)d_out;

    prep_kernel  <<<dim3(BB, 9),  256, 0, stream>>>(feed, emb, W2, xg, w2d);
    layer1_kernel<<<dim3(BB, 32), 256, 0, stream>>>(xg, W1, srm, refk, s1c, Ks, Kr);
    layer2_kernel<<<dim3(BB),     256, 0, stream>>>(s1c, w2d, srm, refk, out, Ks, Kr);
}